// Round 1
// baseline (598.398 us; speedup 1.0000x reference)
//
#include <hip/hip_runtime.h>

#define BLOCK 256
#define PER_THREAD 4
#define C 128

__global__ __launch_bounds__(BLOCK) void MultiCrossEntropyLoss_kernel(
    const float* __restrict__ predicts,
    const int* __restrict__ labels,
    float* __restrict__ out,
    int n, float inv_n)
{
    const int tid = blockIdx.x * BLOCK + threadIdx.x;
    const int i0 = tid * PER_THREAD;

    float s = 0.0f;
    if (i0 + PER_THREAD - 1 < n) {
        // Vector label load (coalesced), then 4 independent gathers (MLP).
        int4 lab = *reinterpret_cast<const int4*>(labels + i0);
        float p0 = predicts[(i0 + 0) * C + lab.x];
        float p1 = predicts[(i0 + 1) * C + lab.y];
        float p2 = predicts[(i0 + 2) * C + lab.z];
        float p3 = predicts[(i0 + 3) * C + lab.w];
        s = __logf(p0) + __logf(p1) + __logf(p2) + __logf(p3);
    } else {
        for (int i = i0; i < n; ++i) {
            s += __logf(predicts[i * C + labels[i]]);
        }
    }

    // Wave (64-lane) shuffle reduction.
    #pragma unroll
    for (int off = 32; off > 0; off >>= 1) {
        s += __shfl_down(s, off, 64);
    }

    // Cross-wave reduction via LDS (BLOCK/64 = 4 waves).
    __shared__ float wave_sums[BLOCK / 64];
    const int lane = threadIdx.x & 63;
    const int wv   = threadIdx.x >> 6;
    if (lane == 0) wave_sums[wv] = s;
    __syncthreads();

    if (threadIdx.x == 0) {
        float bs = wave_sums[0] + wave_sums[1] + wave_sums[2] + wave_sums[3];
        // loss = -(1/N) * sum(log p) ; one atomic per block, pre-scaled.
        atomicAdd(out, -bs * inv_n);
    }
}

extern "C" void kernel_launch(void* const* d_in, const int* in_sizes, int n_in,
                              void* d_out, int out_size, void* d_ws, size_t ws_size,
                              hipStream_t stream) {
    const float* predicts = (const float*)d_in[0];
    const int*   labels   = (const int*)d_in[1];
    float*       out      = (float*)d_out;
    const int n = in_sizes[1];  // N = number of rows/labels

    // d_out is re-poisoned to 0xAA before every timed replay; we accumulate
    // with atomics, so zero it first (hipMemsetAsync is graph-capture-safe).
    hipMemsetAsync(d_out, 0, sizeof(float), stream);

    const int per_block = BLOCK * PER_THREAD;
    const int grid = (n + per_block - 1) / per_block;
    MultiCrossEntropyLoss_kernel<<<grid, BLOCK, 0, stream>>>(
        predicts, labels, out, n, 1.0f / (float)n);
}